// Round 9
// baseline (448.800 us; speedup 1.0000x reference)
//
#include <hip/hip_runtime.h>
#include <math.h>

#define N_NODES 50000
#define N_EDGES 640000
#define F_INDIM 64
#define HDIM 128
#define NLAYERS 3
#define NGRAPH 64
#define NCLS 2
#define SCAN_BLOCKS ((N_NODES + 255) / 256)   // 196
#define POOL_SPLIT 8
#define NTILES (N_NODES / 16)                 // 3125 row-tiles (exact)

typedef __attribute__((ext_vector_type(8))) short bf16x8;   // 8 bf16 (4 VGPRs)
typedef __attribute__((ext_vector_type(4))) float f32x4;

__device__ __forceinline__ float bf_lo(unsigned v) { return __uint_as_float(v << 16); }
__device__ __forceinline__ float bf_hi(unsigned v) { return __uint_as_float(v & 0xffff0000u); }
__device__ __forceinline__ unsigned short f2bf(float f) {
    unsigned b = __float_as_uint(f);
    return (unsigned short)((b + 0x7fffu + ((b >> 16) & 1u)) >> 16);   // RNE
}

// blocked activation layout: [slice = c>>4][node][c & 15], 16 bf16 per (slice,node)
__device__ __forceinline__ size_t aidx(int row, int c) {
    return ((size_t)(c >> 4) * N_NODES + row) * 16 + (c & 15);
}

// ---------------- init / degree / CSR build ----------------

__global__ __launch_bounds__(256) void k_init(int* cnt, float* pool, float* counts) {
    int i = blockIdx.x * 256 + threadIdx.x;
    if (i < N_NODES) cnt[i] = 0;
    if (i < NGRAPH * HDIM) pool[i] = 0.f;
    if (i < NGRAPH) counts[i] = 0.f;
}

// single atomic pass: produces within-dst rank AND the degree histogram (in cnt)
__global__ __launch_bounds__(256) void k_rank(const int* __restrict__ dst,
                                              int* __restrict__ cnt,
                                              int* __restrict__ rank) {
    int e = blockIdx.x * 256 + threadIdx.x;
    if (e < N_EDGES) rank[e] = atomicAdd(&cnt[dst[e]], 1);
}

__global__ __launch_bounds__(256) void k_scan1(const int* __restrict__ hist,
                                               int* __restrict__ row_start,
                                               int* __restrict__ partials,
                                               float* __restrict__ dis) {
    __shared__ int buf[256];
    int i = blockIdx.x * 256 + threadIdx.x;
    int v = (i < N_NODES) ? hist[i] : 0;
    if (i < N_NODES) dis[i] = rsqrtf((float)v + 1.0f);
    buf[threadIdx.x] = v;
    __syncthreads();
#pragma unroll
    for (int off = 1; off < 256; off <<= 1) {
        int t = (threadIdx.x >= off) ? buf[threadIdx.x - off] : 0;
        __syncthreads();
        buf[threadIdx.x] += t;
        __syncthreads();
    }
    if (i < N_NODES) row_start[i] = buf[threadIdx.x] - v;
    if (threadIdx.x == 255) partials[blockIdx.x] = buf[255];
}

__global__ __launch_bounds__(256) void k_scan2(int* __restrict__ partials) {
    __shared__ int buf[256];
    int v = (threadIdx.x < SCAN_BLOCKS) ? partials[threadIdx.x] : 0;
    buf[threadIdx.x] = v;
    __syncthreads();
#pragma unroll
    for (int off = 1; off < 256; off <<= 1) {
        int t = (threadIdx.x >= off) ? buf[threadIdx.x - off] : 0;
        __syncthreads();
        buf[threadIdx.x] += t;
        __syncthreads();
    }
    if (threadIdx.x < SCAN_BLOCKS) partials[threadIdx.x] = buf[threadIdx.x] - v;
}

__global__ __launch_bounds__(256) void k_scan3(int* __restrict__ row_start,
                                               const int* __restrict__ partials) {
    int i = blockIdx.x * 256 + threadIdx.x;
    if (i < N_NODES) row_start[i] += partials[blockIdx.x];
    if (i == 0) row_start[N_NODES] = N_EDGES;
}

// atomic-free placement: position = row_start[dst] + rank; one 8B store per edge
__global__ __launch_bounds__(256) void k_place(const int* __restrict__ src,
                                               const int* __restrict__ dst,
                                               const int* __restrict__ rank,
                                               const float* __restrict__ dis,
                                               const int* __restrict__ row_start,
                                               uint2* __restrict__ csr) {
    int e = blockIdx.x * 256 + threadIdx.x;
    if (e >= N_EDGES) return;
    int s = src[e], d = dst[e];
    uint2 rec;
    rec.x = (unsigned)s;
    rec.y = __float_as_uint(dis[s] * dis[d]);
    csr[row_start[d] + rank[e]] = rec;
}

// ---------------- fp32 -> bf16 conversion, all three tensors in one launch ----------------
#define CVT_Q1 (N_NODES * F_INDIM / 4)
#define CVT_Q2 (CVT_Q1 + HDIM * F_INDIM / 4)
#define CVT_Q3 (CVT_Q2 + NLAYERS * HDIM * HDIM / 4)

__global__ __launch_bounds__(256) void k_cvt_all(const float* __restrict__ x,
                                                 const float* __restrict__ emb_w,
                                                 const float* __restrict__ gcn_w,
                                                 unsigned short* __restrict__ dst0) {
    int i = blockIdx.x * 256 + threadIdx.x;
    if (i >= CVT_Q3) return;
    const float* s;
    int off;
    if (i < CVT_Q1)      { s = x;     off = i; }
    else if (i < CVT_Q2) { s = emb_w; off = i - CVT_Q1; }
    else                 { s = gcn_w; off = i - CVT_Q2; }
    float4 v = *(const float4*)&s[off * 4];
    unsigned r0 = (unsigned)f2bf(v.x) | ((unsigned)f2bf(v.y) << 16);
    unsigned r1 = (unsigned)f2bf(v.z) | ((unsigned)f2bf(v.w) << 16);
    *(uint2*)&dst0[i * 4] = make_uint2(r0, r1);
}

// ---------------- MFMA GEMM: C = A @ W^T (+bias); C written BLOCKED, A flat or blocked ----------------

template<int K, bool BLOCKED_A>
__global__ __launch_bounds__(256) void k_mm(const unsigned short* __restrict__ A,
                                            const unsigned short* __restrict__ W,
                                            const float* __restrict__ bias,
                                            unsigned short* __restrict__ C) {
    constexpr int KS = K / 32;
    int lane = threadIdx.x & 63;
    int lg = lane >> 4, lr = lane & 15;
    int cb = (threadIdx.x >> 6) * 32;          // wave col base
    int tile0 = blockIdx.x * 4;

    bf16x8 wf[2][KS];
#pragma unroll
    for (int ct = 0; ct < 2; ++ct)
#pragma unroll
        for (int ks = 0; ks < KS; ++ks)
            wf[ct][ks] = *(const bf16x8*)&W[(size_t)(cb + ct * 16 + lr) * K + ks * 32 + lg * 8];

    float b0 = bias ? bias[cb + lr] : 0.f;
    float b1 = bias ? bias[cb + 16 + lr] : 0.f;

    int ntile = NTILES - tile0; if (ntile > 4) ntile = 4;
    for (int t = 0; t < ntile; ++t) {
        int rb = (tile0 + t) * 16;
        f32x4 acc0 = {0.f, 0.f, 0.f, 0.f}, acc1 = {0.f, 0.f, 0.f, 0.f};
#pragma unroll
        for (int ks = 0; ks < KS; ++ks) {
            int c0 = ks * 32 + lg * 8;   // 8-channel chunk, never straddles a 16-block
            bf16x8 af = BLOCKED_A
                ? *(const bf16x8*)&A[aidx(rb + lr, c0)]
                : *(const bf16x8*)&A[(size_t)(rb + lr) * K + c0];
            acc0 = __builtin_amdgcn_mfma_f32_16x16x32_bf16(af, wf[0][ks], acc0, 0, 0, 0);
            acc1 = __builtin_amdgcn_mfma_f32_16x16x32_bf16(af, wf[1][ks], acc1, 0, 0, 0);
        }
        int row = rb + lg * 4;
#pragma unroll
        for (int j = 0; j < 4; ++j) {
            C[aidx(row + j, cb + lr)]      = f2bf(acc0[j] + b0);
            C[aidx(row + j, cb + 16 + lr)] = f2bf(acc1[j] + b1);
        }
    }
}

// ---------------- GCN aggregation: XCD-sliced gather over packed CSR ----------------
// blockIdx.x = group*8 + slice; slice -> XCD via round-robin dispatch.
// Each XCD re-reads only its 1.6MB channel slice of hw -> L2-resident.
// wave per (node, slice): lane = edge-sub u (l>>2) x channel-quad p (l&3);
// 16 edges in flight per round; shfl_xor tree reduces edge groups.

__global__ __launch_bounds__(256) void k_gather(const unsigned short* __restrict__ hw,   // blocked
                                                const int* __restrict__ row_start,
                                                const uint2* __restrict__ csr,
                                                const float* __restrict__ dis,
                                                const float* __restrict__ bias,
                                                unsigned short* __restrict__ hout) {     // blocked
    int s = blockIdx.x & 7;                          // channel slice (-> XCD)
    int n = (blockIdx.x >> 3) * 4 + (threadIdx.x >> 6);
    int lane = threadIdx.x & 63;
    int u = lane >> 2;                               // edge sub-index 0..15
    int p = lane & 3;                                // channel quad within slice
    size_t sbase = (size_t)s * N_NODES;
    int beg = row_start[n], end = row_start[n + 1];
    float a0 = 0.f, a1 = 0.f, a2 = 0.f, a3 = 0.f;
    for (int e = beg; e < end; e += 16) {
        int me = e + u;
        uint2 rec = csr[min(me, end - 1)];
        float w = (me < end) ? __uint_as_float(rec.y) : 0.f;
        uint2 v = *(const uint2*)&hw[(sbase + rec.x) * 16 + p * 4];
        a0 += w * bf_lo(v.x); a1 += w * bf_hi(v.x);
        a2 += w * bf_lo(v.y); a3 += w * bf_hi(v.y);
    }
#pragma unroll
    for (int m = 4; m < 64; m <<= 1) {
        a0 += __shfl_xor(a0, m); a1 += __shfl_xor(a1, m);
        a2 += __shfl_xor(a2, m); a3 += __shfl_xor(a3, m);
    }
    if (u == 0) {
        float dn = dis[n], sn = dn * dn;
        uint2 vs = *(const uint2*)&hw[(sbase + n) * 16 + p * 4];
        a0 += sn * bf_lo(vs.x); a1 += sn * bf_hi(vs.x);
        a2 += sn * bf_lo(vs.y); a3 += sn * bf_hi(vs.y);
        float4 b = *(const float4*)&bias[s * 16 + p * 4];
        a0 = fmaxf(a0 + b.x, 0.f); a1 = fmaxf(a1 + b.y, 0.f);
        a2 = fmaxf(a2 + b.z, 0.f); a3 = fmaxf(a3 + b.w, 0.f);
        uint2 r;
        r.x = (unsigned)f2bf(a0) | ((unsigned)f2bf(a1) << 16);
        r.y = (unsigned)f2bf(a2) | ((unsigned)f2bf(a3) << 16);
        *(uint2*)&hout[(sbase + n) * 16 + p * 4] = r;
    }
}

// ---------------- mean-pool: 64 graphs x 8 slices, blocked bf16 input ----------------

__global__ __launch_bounds__(256) void k_pool(const unsigned short* __restrict__ h,
                                              const int* __restrict__ batch,
                                              float* __restrict__ pool,
                                              float* __restrict__ counts) {
    int g  = blockIdx.x >> 3;
    int sp = blockIdx.x & 7;
    int s, e;
    {
        int lo = 0, hi = N_NODES;
        while (lo < hi) { int mid = (lo + hi) >> 1; if (batch[mid] < g) lo = mid + 1; else hi = mid; }
        s = lo;
        lo = s; hi = N_NODES;
        while (lo < hi) { int mid = (lo + hi) >> 1; if (batch[mid] < g + 1) lo = mid + 1; else hi = mid; }
        e = lo;
    }
    int len = e - s;
    int chunk = (len + POOL_SPLIT - 1) / POOL_SPLIT;
    int ss = s + sp * chunk;
    int ee = min(ss + chunk, e);
    int cp = threadIdx.x & 63;   // channel pair: channels 2cp, 2cp+1
    int r  = threadIdx.x >> 6;   // 4 rows
    int c0 = cp * 2;
    float a0 = 0.f, a1 = 0.f;
    for (int n = ss + r; n < ee; n += 4) {
        unsigned v = *(const unsigned*)&h[aidx(n, c0)];
        a0 += bf_lo(v);
        a1 += bf_hi(v);
    }
    __shared__ float red0[4][64], red1[4][64];
    red0[r][cp] = a0; red1[r][cp] = a1;
    __syncthreads();
    if (r == 0) {
#pragma unroll
        for (int j = 1; j < 4; ++j) { a0 += red0[j][cp]; a1 += red1[j][cp]; }
        atomicAdd(&pool[g * HDIM + c0], a0);
        atomicAdd(&pool[g * HDIM + c0 + 1], a1);
    }
    if (threadIdx.x == 0 && ee > ss) atomicAdd(&counts[g], (float)(ee - ss));
}

// ---------------- tail: mean -> LSTM(seq=1) -> attn(v passthrough) -> MLP ----------------

__global__ __launch_bounds__(128) void k_tail(const float* __restrict__ pool,
                                              const float* __restrict__ counts,
                                              const float* __restrict__ w_ih,
                                              const float* __restrict__ b_ih,
                                              const float* __restrict__ b_hh,
                                              const float* __restrict__ attn_in_w,
                                              const float* __restrict__ attn_in_b,
                                              const float* __restrict__ attn_out_w,
                                              const float* __restrict__ attn_out_b,
                                              const float* __restrict__ w1,
                                              const float* __restrict__ b1,
                                              const float* __restrict__ w2,
                                              const float* __restrict__ b2,
                                              float* __restrict__ out) {
    __shared__ float ge[128], hsr[128], vv[128], fe[128], zz[64];
    int g = blockIdx.x, t = threadIdx.x;
    float cnt = fmaxf(counts[g], 1.0f);
    ge[t] = pool[g * HDIM + t] / cnt;
    __syncthreads();
    float gi = 0.f, gg = 0.f, go = 0.f;
    for (int k = 0; k < 128; ++k) {
        float xv = ge[k];
        gi += xv * w_ih[t * HDIM + k];
        gg += xv * w_ih[(256 + t) * HDIM + k];
        go += xv * w_ih[(384 + t) * HDIM + k];
    }
    gi += b_ih[t] + b_hh[t];
    gg += b_ih[256 + t] + b_hh[256 + t];
    go += b_ih[384 + t] + b_hh[384 + t];
    float cc = (1.f / (1.f + expf(-gi))) * tanhf(gg);
    float hv = (1.f / (1.f + expf(-go))) * tanhf(cc);
    hsr[t] = hv;
    __syncthreads();
    float va = attn_in_b[256 + t];
    for (int k = 0; k < 128; ++k) va += hsr[k] * attn_in_w[(256 + t) * HDIM + k];
    vv[t] = va;
    __syncthreads();
    float fv = attn_out_b[t];
    for (int k = 0; k < 128; ++k) fv += vv[k] * attn_out_w[t * HDIM + k];
    fe[t] = fv;
    __syncthreads();
    if (t < 64) {
        float zv = b1[t];
        for (int k = 0; k < 128; ++k) zv += fe[k] * w1[t * HDIM + k];
        zz[t] = fmaxf(zv, 0.f);
    }
    __syncthreads();
    if (t < NCLS) {
        float ov = b2[t];
        for (int k = 0; k < 64; ++k) ov += zz[k] * w2[t * 64 + k];
        out[g * NCLS + t] = ov;
    }
}

// ---------------- launch ----------------

extern "C" void kernel_launch(void* const* d_in, const int* in_sizes, int n_in,
                              void* d_out, int out_size, void* d_ws, size_t ws_size,
                              hipStream_t stream) {
    const float* x          = (const float*)d_in[0];
    const int*   edge_index = (const int*)d_in[1];
    const int*   batch      = (const int*)d_in[2];
    const float* emb_w      = (const float*)d_in[3];
    const float* emb_b      = (const float*)d_in[4];
    const float* gcn_w      = (const float*)d_in[5];
    const float* gcn_b      = (const float*)d_in[6];
    const float* w_ih       = (const float*)d_in[7];
    // d_in[8] = lstm_w_hh (unused: h0 = 0)
    const float* b_ih       = (const float*)d_in[9];
    const float* b_hh       = (const float*)d_in[10];
    const float* attn_in_w  = (const float*)d_in[11];
    const float* attn_in_b  = (const float*)d_in[12];
    const float* attn_out_w = (const float*)d_in[13];
    const float* attn_out_b = (const float*)d_in[14];
    const float* w1         = (const float*)d_in[15];
    const float* b1         = (const float*)d_in[16];
    const float* w2         = (const float*)d_in[17];
    const float* b2         = (const float*)d_in[18];
    float* out = (float*)d_out;

    // ---- workspace layout (words) ----
    int*   iws = (int*)d_ws;
    float* fws = (float*)d_ws;
    int*   cnt       = iws;                          // N   (degree histogram)
    float* dis       = fws + N_NODES;                // N
    int*   row_start = iws + 2 * N_NODES;            // N+1 (pad to 3N+4)
    int*   rank      = iws + 3 * N_NODES + 4;        // E
    uint2* csr       = (uint2*)(iws + 3 * N_NODES + 4 + N_EDGES);  // E recs
    unsigned short* bws   = (unsigned short*)(iws + 3 * N_NODES + 4 + N_EDGES + 2 * N_EDGES);
    unsigned short* x_bf  = bws;                                    // N*64 flat
    unsigned short* we_bf = x_bf + (size_t)N_NODES * F_INDIM;       // 128*64  (contiguous)
    unsigned short* wg_bf = we_bf + HDIM * F_INDIM;                 // 3*128*128 (contiguous)
    unsigned short* hA    = wg_bf + NLAYERS * HDIM * HDIM;          // N*128 blocked [8][N][16]
    unsigned short* hB    = hA + (size_t)N_NODES * HDIM;            // N*128 blocked
    float* pool     = (float*)(hB + (size_t)N_NODES * HDIM);        // 64*128
    float* counts   = pool + NGRAPH * HDIM;                         // 64
    int*   partials = (int*)(counts + NGRAPH);                      // SCAN_BLOCKS

    const int* src = edge_index;
    const int* dst = edge_index + N_EDGES;

    k_init<<<196, 256, 0, stream>>>(cnt, pool, counts);
    k_rank<<<(N_EDGES + 255) / 256, 256, 0, stream>>>(dst, cnt, rank);
    k_scan1<<<SCAN_BLOCKS, 256, 0, stream>>>(cnt, row_start, partials, dis);
    k_scan2<<<1, 256, 0, stream>>>(partials);
    k_scan3<<<SCAN_BLOCKS, 256, 0, stream>>>(row_start, partials);
    k_place<<<(N_EDGES + 255) / 256, 256, 0, stream>>>(src, dst, rank, dis, row_start, csr);

    // one fused conversion pass (x_bf / we_bf / wg_bf are contiguous in ws)
    k_cvt_all<<<(CVT_Q3 + 255) / 256, 256, 0, stream>>>(x, emb_w, gcn_w, x_bf);

    int mm_grid = (NTILES + 3) / 4;   // 782
    k_mm<F_INDIM, false><<<mm_grid, 256, 0, stream>>>(x_bf, we_bf, emb_b, hA);
    for (int l = 0; l < NLAYERS; ++l) {
        k_mm<HDIM, true><<<mm_grid, 256, 0, stream>>>(hA, wg_bf + l * HDIM * HDIM, nullptr, hB);
        k_gather<<<(N_NODES / 4) * 8, 256, 0, stream>>>(hB, row_start, csr, dis,
                                                        gcn_b + l * HDIM, hA);
    }
    k_pool<<<NGRAPH * POOL_SPLIT, 256, 0, stream>>>(hA, batch, pool, counts);
    k_tail<<<NGRAPH, 128, 0, stream>>>(pool, counts, w_ih, b_ih, b_hh,
                                       attn_in_w, attn_in_b, attn_out_w, attn_out_b,
                                       w1, b1, w2, b2, out);
}

// Round 10
// 261.050 us; speedup vs baseline: 1.7192x; 1.7192x over previous
//
#include <hip/hip_runtime.h>
#include <math.h>

#define N_NODES 50000
#define N_EDGES 640000
#define F_INDIM 64
#define HDIM 128
#define NLAYERS 3
#define NGRAPH 64
#define NCLS 2
#define SCAN_BLOCKS ((N_NODES + 255) / 256)   // 196
#define POOL_SPLIT 8
#define NTILES (N_NODES / 16)                 // 3125 row-tiles (exact)

typedef __attribute__((ext_vector_type(8))) short bf16x8;   // 8 bf16 (4 VGPRs)
typedef __attribute__((ext_vector_type(4))) float f32x4;

__device__ __forceinline__ float bf_lo(unsigned v) { return __uint_as_float(v << 16); }
__device__ __forceinline__ float bf_hi(unsigned v) { return __uint_as_float(v & 0xffff0000u); }
__device__ __forceinline__ unsigned short f2bf(float f) {
    unsigned b = __float_as_uint(f);
    return (unsigned short)((b + 0x7fffu + ((b >> 16) & 1u)) >> 16);   // RNE
}

// ---------------- init / degree / CSR build ----------------

__global__ __launch_bounds__(256) void k_init(int* cnt) {
    int i = blockIdx.x * 256 + threadIdx.x;
    if (i < N_NODES) cnt[i] = 0;
}

// single atomic pass: produces within-dst rank AND the degree histogram (in cnt)
__global__ __launch_bounds__(256) void k_rank(const int* __restrict__ dst,
                                              int* __restrict__ cnt,
                                              int* __restrict__ rank) {
    int e = blockIdx.x * 256 + threadIdx.x;
    if (e < N_EDGES) rank[e] = atomicAdd(&cnt[dst[e]], 1);
}

__global__ __launch_bounds__(256) void k_scan1(const int* __restrict__ hist,
                                               int* __restrict__ row_start,
                                               int* __restrict__ partials,
                                               float* __restrict__ dis) {
    __shared__ int buf[256];
    int i = blockIdx.x * 256 + threadIdx.x;
    int v = (i < N_NODES) ? hist[i] : 0;
    if (i < N_NODES) dis[i] = rsqrtf((float)v + 1.0f);
    buf[threadIdx.x] = v;
    __syncthreads();
#pragma unroll
    for (int off = 1; off < 256; off <<= 1) {
        int t = (threadIdx.x >= off) ? buf[threadIdx.x - off] : 0;
        __syncthreads();
        buf[threadIdx.x] += t;
        __syncthreads();
    }
    if (i < N_NODES) row_start[i] = buf[threadIdx.x] - v;
    if (threadIdx.x == 255) partials[blockIdx.x] = buf[255];
}

__global__ __launch_bounds__(256) void k_scan2(int* __restrict__ partials) {
    __shared__ int buf[256];
    int v = (threadIdx.x < SCAN_BLOCKS) ? partials[threadIdx.x] : 0;
    buf[threadIdx.x] = v;
    __syncthreads();
#pragma unroll
    for (int off = 1; off < 256; off <<= 1) {
        int t = (threadIdx.x >= off) ? buf[threadIdx.x - off] : 0;
        __syncthreads();
        buf[threadIdx.x] += t;
        __syncthreads();
    }
    if (threadIdx.x < SCAN_BLOCKS) partials[threadIdx.x] = buf[threadIdx.x] - v;
}

__global__ __launch_bounds__(256) void k_scan3(int* __restrict__ row_start,
                                               const int* __restrict__ partials) {
    int i = blockIdx.x * 256 + threadIdx.x;
    if (i < N_NODES) row_start[i] += partials[blockIdx.x];
    if (i == 0) row_start[N_NODES] = N_EDGES;
}

// ---------------- fused prep: place (atomic-free) + fp32->bf16 cvt + pool zeroing ----------------
// block ranges: [0, PB) place | [PB, PB+CB) cvt | [PB+CB, PB+CB+ZB) zero pool/counts
#define PLACE_BLOCKS ((N_EDGES + 255) / 256)                 // 2500
#define CVT_Q1 (N_NODES * F_INDIM / 4)
#define CVT_Q2 (CVT_Q1 + HDIM * F_INDIM / 4)
#define CVT_Q3 (CVT_Q2 + NLAYERS * HDIM * HDIM / 4)
#define CVT_BLOCKS ((CVT_Q3 + 255) / 256)                    // 3181
#define ZERO_N (NGRAPH * HDIM + NGRAPH)
#define ZERO_BLOCKS ((ZERO_N + 255) / 256)                   // 33

__global__ __launch_bounds__(256) void k_prep(const int* __restrict__ src,
                                              const int* __restrict__ dst,
                                              const int* __restrict__ rank,
                                              const float* __restrict__ dis,
                                              const int* __restrict__ row_start,
                                              uint2* __restrict__ csr,
                                              const float* __restrict__ x,
                                              const float* __restrict__ emb_w,
                                              const float* __restrict__ gcn_w,
                                              unsigned short* __restrict__ dst0,
                                              float* __restrict__ pool_counts) {
    int b = blockIdx.x;
    if (b < PLACE_BLOCKS) {
        int e = b * 256 + threadIdx.x;
        if (e >= N_EDGES) return;
        int s = src[e], d = dst[e];
        uint2 rec;
        rec.x = (unsigned)s;
        rec.y = __float_as_uint(dis[s] * dis[d]);
        csr[row_start[d] + rank[e]] = rec;
    } else if (b < PLACE_BLOCKS + CVT_BLOCKS) {
        int i = (b - PLACE_BLOCKS) * 256 + threadIdx.x;
        if (i >= CVT_Q3) return;
        const float* s;
        int off;
        if (i < CVT_Q1)      { s = x;     off = i; }
        else if (i < CVT_Q2) { s = emb_w; off = i - CVT_Q1; }
        else                 { s = gcn_w; off = i - CVT_Q2; }
        float4 v = *(const float4*)&s[off * 4];
        unsigned r0 = (unsigned)f2bf(v.x) | ((unsigned)f2bf(v.y) << 16);
        unsigned r1 = (unsigned)f2bf(v.z) | ((unsigned)f2bf(v.w) << 16);
        *(uint2*)&dst0[i * 4] = make_uint2(r0, r1);
    } else {
        int i = (b - PLACE_BLOCKS - CVT_BLOCKS) * 256 + threadIdx.x;
        if (i < ZERO_N) pool_counts[i] = 0.f;
    }
}

// ---------------- MFMA GEMM: C[M,128] = A[M,K](bf16) @ W[128,K](bf16)^T (+bias) ----------------

template<int K>
__global__ __launch_bounds__(256) void k_mm(const unsigned short* __restrict__ A,
                                            const unsigned short* __restrict__ W,
                                            const float* __restrict__ bias,
                                            unsigned short* __restrict__ C) {
    constexpr int KS = K / 32;
    int lane = threadIdx.x & 63;
    int lg = lane >> 4, lr = lane & 15;
    int cb = (threadIdx.x >> 6) * 32;          // wave col base
    int tile0 = blockIdx.x * 4;

    bf16x8 wf[2][KS];
#pragma unroll
    for (int ct = 0; ct < 2; ++ct)
#pragma unroll
        for (int ks = 0; ks < KS; ++ks)
            wf[ct][ks] = *(const bf16x8*)&W[(size_t)(cb + ct * 16 + lr) * K + ks * 32 + lg * 8];

    float b0 = bias ? bias[cb + lr] : 0.f;
    float b1 = bias ? bias[cb + 16 + lr] : 0.f;

    int ntile = NTILES - tile0; if (ntile > 4) ntile = 4;
    for (int t = 0; t < ntile; ++t) {
        int rb = (tile0 + t) * 16;
        f32x4 acc0 = {0.f, 0.f, 0.f, 0.f}, acc1 = {0.f, 0.f, 0.f, 0.f};
#pragma unroll
        for (int ks = 0; ks < KS; ++ks) {
            bf16x8 af = *(const bf16x8*)&A[(size_t)(rb + lr) * K + ks * 32 + lg * 8];
            acc0 = __builtin_amdgcn_mfma_f32_16x16x32_bf16(af, wf[0][ks], acc0, 0, 0, 0);
            acc1 = __builtin_amdgcn_mfma_f32_16x16x32_bf16(af, wf[1][ks], acc1, 0, 0, 0);
        }
        int row = rb + lg * 4;
#pragma unroll
        for (int j = 0; j < 4; ++j) {
            C[(size_t)(row + j) * HDIM + cb + lr]      = f2bf(acc0[j] + b0);
            C[(size_t)(row + j) * HDIM + cb + 16 + lr] = f2bf(acc1[j] + b1);
        }
    }
}

// ---------------- GCN aggregation (gather over packed CSR, bf16 in/out) ----------------
// R8-validated structure: wave per node; lanes 0-31 even edges, 32-63 odd edges;
// lane owns a channel quad (8B loads); masked 16-edge round, all loads unconditional.

__global__ __launch_bounds__(256) void k_gather(const unsigned short* __restrict__ hw,
                                                const int* __restrict__ row_start,
                                                const uint2* __restrict__ csr,
                                                const float* __restrict__ dis,
                                                const float* __restrict__ bias,
                                                unsigned short* __restrict__ hout) {
    int n = blockIdx.x * 4 + (threadIdx.x >> 6);
    int lane = threadIdx.x & 63;
    int half = lane >> 5;
    int cl = lane & 31;              // channel quad: channels 4*cl .. 4*cl+3
    int beg = row_start[n], end = row_start[n + 1];
    float a0 = 0.f, a1 = 0.f, a2 = 0.f, a3 = 0.f;
    for (int e = beg; e < end; e += 16) {
        unsigned sidx[8]; float w[8]; uint2 v[8];
#pragma unroll
        for (int u = 0; u < 8; ++u) {
            int me = e + 2 * u + half;
            uint2 rec = csr[min(me, end - 1)];
            sidx[u] = rec.x;
            w[u] = (me < end) ? __uint_as_float(rec.y) : 0.f;
        }
#pragma unroll
        for (int u = 0; u < 8; ++u)
            v[u] = *(const uint2*)&hw[(size_t)sidx[u] * HDIM + cl * 4];
#pragma unroll
        for (int u = 0; u < 8; ++u) {
            a0 += w[u] * bf_lo(v[u].x);
            a1 += w[u] * bf_hi(v[u].x);
            a2 += w[u] * bf_lo(v[u].y);
            a3 += w[u] * bf_hi(v[u].y);
        }
    }
    // cross-half combine (even-edge partial + odd-edge partial)
    a0 += __shfl_xor(a0, 32); a1 += __shfl_xor(a1, 32);
    a2 += __shfl_xor(a2, 32); a3 += __shfl_xor(a3, 32);
    if (half == 0) {
        float dn = dis[n], sn = dn * dn;
        uint2 vs = *(const uint2*)&hw[(size_t)n * HDIM + cl * 4];
        a0 += sn * bf_lo(vs.x); a1 += sn * bf_hi(vs.x);
        a2 += sn * bf_lo(vs.y); a3 += sn * bf_hi(vs.y);
        float4 b = *(const float4*)&bias[cl * 4];
        a0 = fmaxf(a0 + b.x, 0.f); a1 = fmaxf(a1 + b.y, 0.f);
        a2 = fmaxf(a2 + b.z, 0.f); a3 = fmaxf(a3 + b.w, 0.f);
        uint2 r;
        r.x = (unsigned)f2bf(a0) | ((unsigned)f2bf(a1) << 16);
        r.y = (unsigned)f2bf(a2) | ((unsigned)f2bf(a3) << 16);
        *(uint2*)&hout[(size_t)n * HDIM + cl * 4] = r;
    }
}

// ---------------- mean-pool: 64 graphs x 8 slices, bf16 input ----------------

__global__ __launch_bounds__(256) void k_pool(const unsigned short* __restrict__ h,
                                              const int* __restrict__ batch,
                                              float* __restrict__ pool,
                                              float* __restrict__ counts) {
    int g  = blockIdx.x >> 3;
    int sp = blockIdx.x & 7;
    int s, e;
    {
        int lo = 0, hi = N_NODES;
        while (lo < hi) { int mid = (lo + hi) >> 1; if (batch[mid] < g) lo = mid + 1; else hi = mid; }
        s = lo;
        lo = s; hi = N_NODES;
        while (lo < hi) { int mid = (lo + hi) >> 1; if (batch[mid] < g + 1) lo = mid + 1; else hi = mid; }
        e = lo;
    }
    int len = e - s;
    int chunk = (len + POOL_SPLIT - 1) / POOL_SPLIT;
    int ss = s + sp * chunk;
    int ee = min(ss + chunk, e);
    int cp = threadIdx.x & 63;   // channel pair
    int r  = threadIdx.x >> 6;   // 4 rows
    float a0 = 0.f, a1 = 0.f;
    for (int n = ss + r; n < ee; n += 4) {
        unsigned v = *(const unsigned*)&h[(size_t)n * HDIM + cp * 2];
        a0 += bf_lo(v);
        a1 += bf_hi(v);
    }
    __shared__ float red0[4][64], red1[4][64];
    red0[r][cp] = a0; red1[r][cp] = a1;
    __syncthreads();
    if (r == 0) {
#pragma unroll
        for (int j = 1; j < 4; ++j) { a0 += red0[j][cp]; a1 += red1[j][cp]; }
        atomicAdd(&pool[g * HDIM + cp * 2], a0);
        atomicAdd(&pool[g * HDIM + cp * 2 + 1], a1);
    }
    if (threadIdx.x == 0 && ee > ss) atomicAdd(&counts[g], (float)(ee - ss));
}

// ---------------- tail: mean -> LSTM(seq=1) -> attn(v passthrough) -> MLP ----------------

__global__ __launch_bounds__(128) void k_tail(const float* __restrict__ pool,
                                              const float* __restrict__ counts,
                                              const float* __restrict__ w_ih,
                                              const float* __restrict__ b_ih,
                                              const float* __restrict__ b_hh,
                                              const float* __restrict__ attn_in_w,
                                              const float* __restrict__ attn_in_b,
                                              const float* __restrict__ attn_out_w,
                                              const float* __restrict__ attn_out_b,
                                              const float* __restrict__ w1,
                                              const float* __restrict__ b1,
                                              const float* __restrict__ w2,
                                              const float* __restrict__ b2,
                                              float* __restrict__ out) {
    __shared__ float ge[128], hsr[128], vv[128], fe[128], zz[64];
    int g = blockIdx.x, t = threadIdx.x;
    float cnt = fmaxf(counts[g], 1.0f);
    ge[t] = pool[g * HDIM + t] / cnt;
    __syncthreads();
    float gi = 0.f, gg = 0.f, go = 0.f;
    for (int k = 0; k < 128; ++k) {
        float xv = ge[k];
        gi += xv * w_ih[t * HDIM + k];
        gg += xv * w_ih[(256 + t) * HDIM + k];
        go += xv * w_ih[(384 + t) * HDIM + k];
    }
    gi += b_ih[t] + b_hh[t];
    gg += b_ih[256 + t] + b_hh[256 + t];
    go += b_ih[384 + t] + b_hh[384 + t];
    float cc = (1.f / (1.f + expf(-gi))) * tanhf(gg);
    float hv = (1.f / (1.f + expf(-go))) * tanhf(cc);
    hsr[t] = hv;
    __syncthreads();
    float va = attn_in_b[256 + t];
    for (int k = 0; k < 128; ++k) va += hsr[k] * attn_in_w[(256 + t) * HDIM + k];
    vv[t] = va;
    __syncthreads();
    float fv = attn_out_b[t];
    for (int k = 0; k < 128; ++k) fv += vv[k] * attn_out_w[t * HDIM + k];
    fe[t] = fv;
    __syncthreads();
    if (t < 64) {
        float zv = b1[t];
        for (int k = 0; k < 128; ++k) zv += fe[k] * w1[t * HDIM + k];
        zz[t] = fmaxf(zv, 0.f);
    }
    __syncthreads();
    if (t < NCLS) {
        float ov = b2[t];
        for (int k = 0; k < 64; ++k) ov += zz[k] * w2[t * 64 + k];
        out[g * NCLS + t] = ov;
    }
}

// ---------------- launch ----------------

extern "C" void kernel_launch(void* const* d_in, const int* in_sizes, int n_in,
                              void* d_out, int out_size, void* d_ws, size_t ws_size,
                              hipStream_t stream) {
    const float* x          = (const float*)d_in[0];
    const int*   edge_index = (const int*)d_in[1];
    const int*   batch      = (const int*)d_in[2];
    const float* emb_w      = (const float*)d_in[3];
    const float* emb_b      = (const float*)d_in[4];
    const float* gcn_w      = (const float*)d_in[5];
    const float* gcn_b      = (const float*)d_in[6];
    const float* w_ih       = (const float*)d_in[7];
    // d_in[8] = lstm_w_hh (unused: h0 = 0)
    const float* b_ih       = (const float*)d_in[9];
    const float* b_hh       = (const float*)d_in[10];
    const float* attn_in_w  = (const float*)d_in[11];
    const float* attn_in_b  = (const float*)d_in[12];
    const float* attn_out_w = (const float*)d_in[13];
    const float* attn_out_b = (const float*)d_in[14];
    const float* w1         = (const float*)d_in[15];
    const float* b1         = (const float*)d_in[16];
    const float* w2         = (const float*)d_in[17];
    const float* b2         = (const float*)d_in[18];
    float* out = (float*)d_out;

    // ---- workspace layout (words) ----
    int*   iws = (int*)d_ws;
    float* fws = (float*)d_ws;
    int*   cnt       = iws;                          // N   (degree histogram)
    float* dis       = fws + N_NODES;                // N
    int*   row_start = iws + 2 * N_NODES;            // N+1 (pad to 3N+4)
    int*   rank      = iws + 3 * N_NODES + 4;        // E
    uint2* csr       = (uint2*)(iws + 3 * N_NODES + 4 + N_EDGES);  // E recs
    unsigned short* bws   = (unsigned short*)(iws + 3 * N_NODES + 4 + N_EDGES + 2 * N_EDGES);
    unsigned short* x_bf  = bws;                                    // N*64 flat
    unsigned short* we_bf = x_bf + (size_t)N_NODES * F_INDIM;       // 128*64  (contiguous)
    unsigned short* wg_bf = we_bf + HDIM * F_INDIM;                 // 3*128*128 (contiguous)
    unsigned short* hA    = wg_bf + NLAYERS * HDIM * HDIM;          // N*128
    unsigned short* hB    = hA + (size_t)N_NODES * HDIM;            // N*128
    float* pool     = (float*)(hB + (size_t)N_NODES * HDIM);        // 64*128
    float* counts   = pool + NGRAPH * HDIM;                         // 64 (contiguous with pool)
    int*   partials = (int*)(counts + NGRAPH);                      // SCAN_BLOCKS

    const int* src = edge_index;
    const int* dst = edge_index + N_EDGES;

    k_init<<<196, 256, 0, stream>>>(cnt);
    k_rank<<<(N_EDGES + 255) / 256, 256, 0, stream>>>(dst, cnt, rank);
    k_scan1<<<SCAN_BLOCKS, 256, 0, stream>>>(cnt, row_start, partials, dis);
    k_scan2<<<1, 256, 0, stream>>>(partials);
    k_scan3<<<SCAN_BLOCKS, 256, 0, stream>>>(row_start, partials);

    // fused: place + cvt + pool/counts zero (independent units, one launch)
    k_prep<<<PLACE_BLOCKS + CVT_BLOCKS + ZERO_BLOCKS, 256, 0, stream>>>(
        src, dst, rank, dis, row_start, csr, x, emb_w, gcn_w, x_bf, pool);

    int mm_grid = (NTILES + 3) / 4;   // 782
    k_mm<F_INDIM><<<mm_grid, 256, 0, stream>>>(x_bf, we_bf, emb_b, hA);
    for (int l = 0; l < NLAYERS; ++l) {
        k_mm<HDIM><<<mm_grid, 256, 0, stream>>>(hA, wg_bf + l * HDIM * HDIM, nullptr, hB);
        k_gather<<<N_NODES / 4, 256, 0, stream>>>(hB, row_start, csr, dis,
                                                  gcn_b + l * HDIM, hA);
    }
    k_pool<<<NGRAPH * POOL_SPLIT, 256, 0, stream>>>(hA, batch, pool, counts);
    k_tail<<<NGRAPH, 128, 0, stream>>>(pool, counts, w_ih, b_ih, b_hh,
                                       attn_in_w, attn_in_b, attn_out_w, attn_out_b,
                                       w1, b1, w2, b2, out);
}